// Round 3
// baseline (1242.287 us; speedup 1.0000x reference)
//
#include <hip/hip_runtime.h>

// ---------------------------------------------------------------------------
// SegFormerXAttention on MI355X (gfx950)
//  B=4, Lv=1024, Lt=256, D=1024, H=16, DH=64, L=Lv+Lt=1280
//  Dataset dtypes (established round 2): ALL float tensors fp32, masks int32,
//  output fp32. (Threshold = 2% * max|ref| exactly -> generic fp32 rule.)
//  Stage 1: 12 projections, fp32 inputs staged to LDS via global_load_lds,
//           converted to fp16 fragments, f16 MFMA -> Q/K/V in fp16 workspace.
//  Stage 2: single-pass online-softmax flash attention (f16 MFMA), fp32 out.
// ---------------------------------------------------------------------------

typedef __attribute__((ext_vector_type(8))) _Float16  half8;    // 8 x f16
typedef __attribute__((ext_vector_type(4))) float     f32x4;

#define MFMA_F16  __builtin_amdgcn_mfma_f32_16x16x32_f16

static __device__ __forceinline__ unsigned short f_to_f16u(float f) {
  _Float16 h = (_Float16)f;
  return __builtin_bit_cast(unsigned short, h);
}

#define GLOAD_LDS16(g, l)                                            \
  __builtin_amdgcn_global_load_lds(                                  \
      (const __attribute__((address_space(1))) void*)(g),            \
      (__attribute__((address_space(3))) void*)(l), 16, 0, 0)

// convert 8 consecutive fp32 (32B-aligned LDS) to a f16x8 fragment
static __device__ __forceinline__ half8 cvt8(const float* p) {
  const f32x4 a = *(const f32x4*)p;
  const f32x4 b = *(const f32x4*)(p + 4);
  half8 h;
  h[0] = (_Float16)a[0]; h[1] = (_Float16)a[1];
  h[2] = (_Float16)a[2]; h[3] = (_Float16)a[3];
  h[4] = (_Float16)b[0]; h[5] = (_Float16)b[1];
  h[6] = (_Float16)b[2]; h[7] = (_Float16)b[3];
  return h;
}

// ---------------------------------------------------------------------------
// Projection GEMM:  Y[m,n] = sum_d X[m,d] * W[n,d] + bias[n]
// X: [M,1024] fp32 row-major; W: [1024,1024] fp32 row-major (o-major) == B^T.
// Epilogue scatters fp16 into attention layouts.
//   mode 0: dst[((b*16+h)*Ld + soff + l)*64 + dh]      (Q / K, seq-major)
//   mode 1: dst[((b*16+h)*64 + dh)*Ld + soff + l]      (V transposed)
// ---------------------------------------------------------------------------
struct ProjDesc {
  const float* X;
  const float* W;
  const float* Bv;
  unsigned short* dst;
  int M, lxsh, Ld, soff, mode;
};
struct ProjArgs { ProjDesc d[12]; };

__global__ __launch_bounds__(256) void proj_gemm(ProjArgs pa) {
  const ProjDesc dd = pa.d[blockIdx.z];
  const int m0 = blockIdx.y * 128;
  if (m0 >= dd.M) return;                       // txt projections: M=1024
  const int n0 = blockIdx.x * 128;

  __shared__ __align__(16) float As[128 * 32];   // 16 KB
  __shared__ __align__(16) float Bs[128 * 32];   // 16 KB

  const int tid  = threadIdx.x;
  const int lane = tid & 63;
  const int w    = tid >> 6;          // wave 0..3
  const int wr   = (w >> 1) * 64;     // wave row offset in 128-tile
  const int wc   = (w & 1) * 64;      // wave col offset
  const int ql   = lane & 15;
  const int qd   = lane >> 4;

  f32x4 acc[4][4];
  for (int i = 0; i < 4; ++i)
    for (int j = 0; j < 4; ++j) acc[i][j] = (f32x4)(0.0f);

  const float* Xg = dd.X + (size_t)m0 * 1024;
  const float* Wg = dd.W + (size_t)n0 * 1024;

  for (int k0 = 0; k0 < 1024; k0 += 32) {
    __syncthreads();   // previous iter's LDS reads done before overwrite
    // stage 128x32 fp32 tiles: 1024 chunks of 16B (4 floats); 4 chunks/thread
    for (int j = 0; j < 4; ++j) {
      const int cb  = (j * 4 + w) * 64;          // wave-uniform chunk base
      const int c   = cb + lane;
      const int row = c >> 3;
      const int col = (c & 7) << 2;
      GLOAD_LDS16(Xg + row * 1024 + k0 + col, As + cb * 4);
      GLOAD_LDS16(Wg + row * 1024 + k0 + col, Bs + cb * 4);
    }
    __syncthreads();   // drains vmcnt (global_load_lds) + barrier

    half8 af[4], bf[4];
    for (int mt = 0; mt < 4; ++mt)
      af[mt] = cvt8(&As[(wr + mt * 16 + ql) * 32 + qd * 8]);
    for (int nt = 0; nt < 4; ++nt)
      bf[nt] = cvt8(&Bs[(wc + nt * 16 + ql) * 32 + qd * 8]);
    for (int mt = 0; mt < 4; ++mt)
      for (int nt = 0; nt < 4; ++nt)
        acc[mt][nt] = MFMA_F16(af[mt], bf[nt], acc[mt][nt], 0, 0, 0);
  }

  float bv[4];
  for (int nt = 0; nt < 4; ++nt)
    bv[nt] = dd.Bv[n0 + wc + nt * 16 + ql];

  const int lmask = (1 << dd.lxsh) - 1;
  for (int mt = 0; mt < 4; ++mt) {
    const int mbase = m0 + wr + mt * 16 + qd * 4;
    for (int nt = 0; nt < 4; ++nt) {
      const int n  = n0 + wc + nt * 16 + ql;
      const int h  = n >> 6;
      const int dh = n & 63;
      for (int r = 0; r < 4; ++r) {
        const int mm = mbase + r;
        const int b  = mm >> dd.lxsh;
        const int l  = mm & lmask;
        const float v = acc[mt][nt][r] + bv[nt];
        size_t idx;
        if (dd.mode == 0)
          idx = ((size_t)(b * 16 + h) * dd.Ld + dd.soff + l) * 64 + dh;
        else
          idx = ((size_t)(b * 16 + h) * 64 + dh) * (size_t)dd.Ld + dd.soff + l;
        dd.dst[idx] = f_to_f16u(v);
      }
    }
  }
}

// ---------------------------------------------------------------------------
// Single-pass flash attention. Per wave: 16 query rows.
//  Per 32-key block: S via f16 MFMA (C-layout: row=qd*4+r, col=ql), mask to
//  -10000, online (m,l) update with row-max merged across the 16 ql-lanes,
//  P (fp16, <=1) -> LDS -> A-layout read, PV MFMA against VT.
//  Epilogue: out = o * 0.125 / l  (fp32). NaN-impossible: exp args <= 0, l>=1.
//  Qa: query proj used for keys [0,1024); Qb: for keys [1024,1280).
//  Layouts: Q [bh][Lq][64] f16, K [bh][1280][64] f16, VT [bh][64][1280] f16.
// ---------------------------------------------------------------------------
__global__ __launch_bounds__(256) void attn_flash(
    const unsigned short* __restrict__ Qa, const unsigned short* __restrict__ Qb,
    const unsigned short* __restrict__ K,  const unsigned short* __restrict__ VT,
    const int* __restrict__ mq, const int* __restrict__ mkv,
    const int* __restrict__ mkt,
    float* __restrict__ out, int Lq) {
  __shared__ __align__(16) unsigned short Ps[4 * 512];   // 4 KB, 16x32 / wave

  const int bh = blockIdx.y;
  const int b  = bh >> 4;
  const int h  = bh & 15;
  const int w    = threadIdx.x >> 6;
  const int lane = threadIdx.x & 63;
  const int ql = lane & 15, qd = lane >> 4;
  const int q0 = blockIdx.x * 64 + w * 16;

  const unsigned short* Qab = Qa + ((size_t)bh * Lq + q0) * 64;
  const unsigned short* Qbb = Qb + ((size_t)bh * Lq + q0) * 64;
  half8 aA[2], aB[2];
  for (int ks = 0; ks < 2; ++ks) {
    aA[ks] = *(const half8*)&Qab[ql * 64 + ks * 32 + qd * 8];
    aB[ks] = *(const half8*)&Qbb[ql * 64 + ks * 32 + qd * 8];
  }
  int mqr[4];
  for (int r = 0; r < 4; ++r) mqr[r] = mq[b * Lq + q0 + qd * 4 + r];

  float m[4], l[4];
  for (int r = 0; r < 4; ++r) { m[r] = -1e30f; l[r] = 0.0f; }
  f32x4 o[4];
  for (int nt = 0; nt < 4; ++nt) o[nt] = (f32x4)(0.0f);

  const unsigned short* Kb = K  + (size_t)bh * 1280 * 64;
  const unsigned short* Vb = VT + (size_t)bh * 64 * 1280;
  unsigned short* myP = Ps + w * 512;

  for (int k0 = 0; k0 < 1280; k0 += 32) {
    const bool vidp = (k0 < 1024);
    float sv[2][4];
    for (int sub = 0; sub < 2; ++sub) {
      const int kb = k0 + sub * 16;
      const half8 bf0 = *(const half8*)&Kb[(kb + ql) * 64 + qd * 8];
      const half8 bf1 = *(const half8*)&Kb[(kb + ql) * 64 + 32 + qd * 8];
      f32x4 S = (f32x4)(0.0f);
      if (vidp) { S = MFMA_F16(aA[0], bf0, S, 0, 0, 0); S = MFMA_F16(aA[1], bf1, S, 0, 0, 0); }
      else      { S = MFMA_F16(aB[0], bf0, S, 0, 0, 0); S = MFMA_F16(aB[1], bf1, S, 0, 0, 0); }
      const int kk = kb + ql;
      const int mk = vidp ? mkv[b * 1024 + kk] : mkt[b * 256 + kk - 1024];
      for (int r = 0; r < 4; ++r)
        sv[sub][r] = (mk && mqr[r]) ? S[r] : -10000.0f;
    }
    // block row-max: local pair-max, then merge across the 16 ql-lanes
    float bm[4];
    for (int r = 0; r < 4; ++r) bm[r] = fmaxf(sv[0][r], sv[1][r]);
    for (int off = 1; off < 16; off <<= 1)
      for (int r = 0; r < 4; ++r)
        bm[r] = fmaxf(bm[r], __shfl_xor(bm[r], off, 64));
    // online update
    float alpha[4];
    for (int r = 0; r < 4; ++r) {
      const float nm = fmaxf(m[r], bm[r]);
      alpha[r] = __expf(m[r] - nm);      // first block: exp(-1e30) = 0
      m[r] = nm;
    }
    for (int sub = 0; sub < 2; ++sub)
      for (int r = 0; r < 4; ++r) {
        const float p = __expf(sv[sub][r] - m[r]);   // arg <= 0 always
        sv[sub][r] = p;
        myP[(qd * 4 + r) * 32 + sub * 16 + ql] = f_to_f16u(p);
      }
    for (int r = 0; r < 4; ++r)
      l[r] = l[r] * alpha[r] + sv[0][r] + sv[1][r];
    for (int nt = 0; nt < 4; ++nt)
      for (int r = 0; r < 4; ++r) o[nt][r] *= alpha[r];

    __syncthreads();   // P C-layout writes visible before A-layout reads
    const half8 pA = *(const half8*)&myP[ql * 32 + qd * 8];
    for (int nt = 0; nt < 4; ++nt) {
      const half8 vf = *(const half8*)&Vb[(nt * 16 + ql) * 1280 + k0 + qd * 8];
      o[nt] = MFMA_F16(pA, vf, o[nt], 0, 0, 0);
    }
    __syncthreads();   // reads done before next iteration overwrites
  }

  // merge partial l across the 16 ql-lanes (all lanes share m[r] already)
  for (int off = 1; off < 16; off <<= 1)
    for (int r = 0; r < 4; ++r)
      l[r] += __shfl_xor(l[r], off, 64);

  for (int nt = 0; nt < 4; ++nt) {
    const int dh = nt * 16 + ql;
    for (int r = 0; r < 4; ++r) {
      const int q = q0 + qd * 4 + r;
      const size_t idx = ((size_t)(b * Lq + q)) * 1024 + h * 64 + dh;
      out[idx] = o[nt][r] * 0.125f / l[r];   // l >= 1 always
    }
  }
}

// ---------------------------------------------------------------------------
extern "C" void kernel_launch(void* const* d_in, const int* in_sizes, int n_in,
                              void* d_out, int out_size, void* d_ws, size_t ws_size,
                              hipStream_t stream) {
  const float* vid   = (const float*)d_in[0];
  const int*   vmask = (const int*)d_in[1];
  const float* txt   = (const float*)d_in[2];
  const int*   tmask = (const int*)d_in[3];
  const float* W_v2v = (const float*)d_in[4];
  const float* b_v2v = (const float*)d_in[5];
  const float* W_t2v = (const float*)d_in[6];
  const float* b_t2v = (const float*)d_in[7];
  const float* W_v2t = (const float*)d_in[8];
  const float* b_v2t = (const float*)d_in[9];
  const float* W_t2t = (const float*)d_in[10];
  const float* b_t2t = (const float*)d_in[11];

  const int DD = 1024 * 1024, Dm = 1024;

  unsigned short* ws = (unsigned short*)d_ws;
  unsigned short* Qa_v = ws;                       // 4,194,304 elems (f16)
  unsigned short* Qb_v = ws + 4194304;             // 4,194,304
  unsigned short* K_v  = ws + 8388608;             // 5,242,880
  unsigned short* V_vT = ws + 13631488;            // 5,242,880
  unsigned short* Qa_t = ws + 18874368;            // 1,048,576
  unsigned short* Qb_t = ws + 19922944;            // 1,048,576
  unsigned short* K_t  = ws + 20971520;            // 5,242,880
  unsigned short* V_tT = ws + 26214400;            // 5,242,880  (end 31,457,280)

  ProjArgs pa;
  auto set = [&](int i, const float* X, const float* W, const float* Bv,
                 unsigned short* dst, int M, int lxsh, int Ld, int soff, int mode) {
    pa.d[i] = ProjDesc{X, W, Bv, dst, M, lxsh, Ld, soff, mode};
  };
  //    idx  X    W              bias          dst    M     lxsh Ld    soff  mode
  set(0,  vid, W_v2v,          b_v2v,          Qa_v, 4096, 10, 1024, 0,    0);
  set(1,  vid, W_v2v + DD,     b_v2v + Dm,     K_v,  4096, 10, 1280, 0,    0);
  set(2,  vid, W_v2v + 2 * DD, b_v2v + 2 * Dm, V_vT, 4096, 10, 1280, 0,    1);
  set(3,  vid, W_t2v,          b_t2v,          Qb_v, 4096, 10, 1024, 0,    0);
  set(4,  txt, W_t2v + DD,     b_t2v + Dm,     K_v,  1024, 8,  1280, 1024, 0);
  set(5,  txt, W_t2v + 2 * DD, b_t2v + 2 * Dm, V_vT, 1024, 8,  1280, 1024, 1);
  set(6,  txt, W_v2t,          b_v2t,          Qa_t, 1024, 8,  256,  0,    0);
  set(7,  vid, W_v2t + DD,     b_v2t + Dm,     K_t,  4096, 10, 1280, 0,    0);
  set(8,  vid, W_v2t + 2 * DD, b_v2t + 2 * Dm, V_tT, 4096, 10, 1280, 0,    1);
  set(9,  txt, W_t2t,          b_t2t,          Qb_t, 1024, 8,  256,  0,    0);
  set(10, txt, W_t2t + DD,     b_t2t + Dm,     K_t,  1024, 8,  1280, 1024, 0);
  set(11, txt, W_t2t + 2 * DD, b_t2t + 2 * Dm, V_tT, 1024, 8,  1280, 1024, 1);

  proj_gemm<<<dim3(8, 32, 12), dim3(256), 0, stream>>>(pa);

  float* out_v = (float*)d_out;
  float* out_t = out_v + 4 * 1024 * 1024;
  attn_flash<<<dim3(16, 64), dim3(256), 0, stream>>>(
      Qa_v, Qb_v, K_v, V_vT, vmask, vmask, tmask, out_v, 1024);
  attn_flash<<<dim3(4, 64), dim3(256), 0, stream>>>(
      Qa_t, Qb_t, K_t, V_tT, tmask, vmask, tmask, out_t, 256);
}

// Round 5
// 530.838 us; speedup vs baseline: 2.3402x; 2.3402x over previous
//
#include <hip/hip_runtime.h>

// ---------------------------------------------------------------------------
// SegFormerXAttention on MI355X (gfx950)
//  B=4, Lv=1024, Lt=256, D=1024, H=16, DH=64, L=Lv+Lt=1280
//  fp32 inputs/outputs, int32 masks (verified round 3: absmax 3.9e-3 pass).
//  Stage 1: 12 projections, fp32 staged via global_load_lds (+16B XOR swizzle
//           to kill LDS bank conflicts), f16 MFMA, LDS-transposed epilogue
//           with coalesced 16-B stores -> Q/K/V fp16 workspace.
//           (Round-3 counters: 3.9 GB HBM writes from 2-B scatter = 60x
//            amplification; this round removes it.)
//  Stage 2: single-pass online-softmax flash attention (f16 MFMA), fp32 out.
//  (Round 4 = round-4 source resubmitted unchanged after container flake.)
// ---------------------------------------------------------------------------

typedef __attribute__((ext_vector_type(8))) _Float16  half8;    // 8 x f16
typedef __attribute__((ext_vector_type(4))) float     f32x4;
typedef __attribute__((ext_vector_type(4))) unsigned int uint4v;

#define MFMA_F16  __builtin_amdgcn_mfma_f32_16x16x32_f16

static __device__ __forceinline__ unsigned short f_to_f16u(float f) {
  _Float16 h = (_Float16)f;
  return __builtin_bit_cast(unsigned short, h);
}

#define GLOAD_LDS16(g, l)                                            \
  __builtin_amdgcn_global_load_lds(                                  \
      (const __attribute__((address_space(1))) void*)(g),            \
      (__attribute__((address_space(3))) void*)(l), 16, 0, 0)

// ---------------------------------------------------------------------------
// Projection GEMM:  Y[m,n] = sum_d X[m,d] * W[n,d] + bias[n]
// X: [M,1024] fp32 row-major; W: [1024,1024] fp32 row-major (o-major) == B^T.
// Staged tiles are 128x32 fp32, stored as 16-B chunks with kc ^= (row&7)
// swizzle (applied to the GLOBAL source chunk so global_load_lds's lane-
// linear LDS destination is preserved; same 128-B/row global footprint).
// Epilogue: C tile -> LDS fp16 (mode 0: m-major, mode 1: n-major), then
// uniform 16-B-chunk copy-out, fully coalesced in the destination layout:
//   mode 0: dst[((b*16+h)*Ld + soff + l)*64 + dh]      (Q / K, seq-major)
//   mode 1: dst[((b*16+h)*64 + dh)*Ld + soff + l]      (V transposed)
// ---------------------------------------------------------------------------
struct ProjDesc {
  const float* X;
  const float* W;
  const float* Bv;
  unsigned short* dst;
  int M, lxsh, Ld, soff, mode;
};
struct ProjArgs { ProjDesc d[12]; };

// read 8 fp32 (two swizzled 16-B chunks) from a staged tile, convert to f16x8
static __device__ __forceinline__ half8 cvt8sw(const float* base, int row, int g0) {
  const int sw = row & 7;
  const f32x4 a = *(const f32x4*)(base + (row * 8 + (g0 ^ sw)) * 4);
  const f32x4 b = *(const f32x4*)(base + (row * 8 + ((g0 + 1) ^ sw)) * 4);
  half8 h;
  h[0] = (_Float16)a[0]; h[1] = (_Float16)a[1];
  h[2] = (_Float16)a[2]; h[3] = (_Float16)a[3];
  h[4] = (_Float16)b[0]; h[5] = (_Float16)b[1];
  h[6] = (_Float16)b[2]; h[7] = (_Float16)b[3];
  return h;
}

__global__ __launch_bounds__(256) void proj_gemm(ProjArgs pa) {
  const ProjDesc dd = pa.d[blockIdx.z];
  const int m0 = blockIdx.y * 128;
  if (m0 >= dd.M) return;                       // txt projections: M=1024
  const int n0 = blockIdx.x * 128;

  // union: staging (2 x 16 KB fp32) / epilogue C-tile (128 x 136 halfs)
  __shared__ __align__(16) unsigned char smem[34816];
  float* As = (float*)smem;            // 128*32 fp32, chunk-swizzled
  float* Bs = As + 4096;
  unsigned short* Cs = (unsigned short*)smem;

  const int tid  = threadIdx.x;
  const int lane = tid & 63;
  const int w    = tid >> 6;          // wave 0..3
  const int wr   = (w >> 1) * 64;     // wave row offset in 128-tile
  const int wc   = (w & 1) * 64;      // wave col offset
  const int ql   = lane & 15;
  const int qd   = lane >> 4;

  f32x4 acc[4][4];
  for (int i = 0; i < 4; ++i)
    for (int j = 0; j < 4; ++j) acc[i][j] = (f32x4)(0.0f);

  const float* Xg = dd.X + (size_t)m0 * 1024;
  const float* Wg = dd.W + (size_t)n0 * 1024;

  for (int k0 = 0; k0 < 1024; k0 += 32) {
    __syncthreads();   // previous iter's LDS reads done before overwrite
    // stage 128x32 fp32: 1024 chunks of 16B; 4 per thread; swizzled source
    for (int j = 0; j < 4; ++j) {
      const int cb  = (j * 4 + w) * 64;          // wave-uniform chunk base
      const int c   = cb + lane;
      const int row = c >> 3;
      const int kcg = (c & 7) ^ (row & 7);       // swizzled global chunk
      GLOAD_LDS16(Xg + row * 1024 + k0 + kcg * 4, As + cb * 4);
      GLOAD_LDS16(Wg + row * 1024 + k0 + kcg * 4, Bs + cb * 4);
    }
    __syncthreads();   // drains vmcnt (global_load_lds) + barrier

    half8 af[4], bf[4];
    for (int mt = 0; mt < 4; ++mt)
      af[mt] = cvt8sw(As, wr + mt * 16 + ql, qd * 2);
    for (int nt = 0; nt < 4; ++nt)
      bf[nt] = cvt8sw(Bs, wc + nt * 16 + ql, qd * 2);
    for (int mt = 0; mt < 4; ++mt)
      for (int nt = 0; nt < 4; ++nt)
        acc[mt][nt] = MFMA_F16(af[mt], bf[nt], acc[mt][nt], 0, 0, 0);
  }

  float bv[4];
  for (int nt = 0; nt < 4; ++nt)
    bv[nt] = dd.Bv[n0 + wc + nt * 16 + ql];

  __syncthreads();   // all waves done reading As/Bs before Cs overwrite

  // write C tile to LDS fp16. mode 0: row=mlocal,col=nlocal; mode 1: swapped.
  // phys halfword addr = row*136 + ((col>>3) ^ (row&7))*8 + (col&7)
  for (int mt = 0; mt < 4; ++mt) {
    for (int nt = 0; nt < 4; ++nt) {
      const int nl = wc + nt * 16 + ql;
      for (int r = 0; r < 4; ++r) {
        const int ml = wr + mt * 16 + qd * 4 + r;
        const int row = dd.mode == 0 ? ml : nl;
        const int col = dd.mode == 0 ? nl : ml;
        const float v = acc[mt][nt][r] + bv[nt];
        Cs[row * 136 + (((col >> 3) ^ (row & 7)) << 3) + (col & 7)] = f_to_f16u(v);
      }
    }
  }
  __syncthreads();

  // copy-out: 2048 16-B chunks, 8 per thread, coalesced destination runs
  const int b    = m0 >> dd.lxsh;          // block-uniform (tiles don't cross b)
  const int l0   = m0 & ((1 << dd.lxsh) - 1);
  const int h0   = n0 >> 6;
  const int bh0  = b * 16 + h0;
  for (int i = 0; i < 8; ++i) {
    const int c     = i * 256 + tid;
    const int major = c >> 4;                // mode0: mlocal, mode1: nlocal
    const int kc    = c & 15;
    const uint4v val =
        *(const uint4v*)&Cs[major * 136 + ((kc ^ (major & 7)) << 3)];
    size_t el;
    if (dd.mode == 0) {
      const int hs   = kc >> 3;
      const int koff = kc & 7;
      el = ((size_t)(bh0 + hs) * dd.Ld + dd.soff + l0 + major) * 64 + koff * 8;
    } else {
      const int h  = h0 + (major >> 6);
      const int dh = major & 63;
      el = ((size_t)(b * 16 + h) * 64 + dh) * (size_t)dd.Ld + dd.soff + l0 + kc * 8;
    }
    *(uint4v*)(dd.dst + el) = val;
  }
}

// ---------------------------------------------------------------------------
// Single-pass flash attention. Per wave: 16 query rows.
//  Per 32-key block: S via f16 MFMA (C-layout: row=qd*4+r, col=ql), mask to
//  -10000, online (m,l) update with row-max merged across the 16 ql-lanes,
//  P (fp16, <=1) -> LDS -> A-layout read, PV MFMA against VT.
//  Epilogue: out = o * 0.125 / l  (fp32). NaN-impossible: exp args <= 0, l>=1.
//  Qa: query proj used for keys [0,1024); Qb: for keys [1024,1280).
//  Layouts: Q [bh][Lq][64] f16, K [bh][1280][64] f16, VT [bh][64][1280] f16.
// ---------------------------------------------------------------------------
__global__ __launch_bounds__(256) void attn_flash(
    const unsigned short* __restrict__ Qa, const unsigned short* __restrict__ Qb,
    const unsigned short* __restrict__ K,  const unsigned short* __restrict__ VT,
    const int* __restrict__ mq, const int* __restrict__ mkv,
    const int* __restrict__ mkt,
    float* __restrict__ out, int Lq) {
  __shared__ __align__(16) unsigned short Ps[4 * 512];   // 4 KB, 16x32 / wave

  const int bh = blockIdx.y;
  const int b  = bh >> 4;
  const int h  = bh & 15;
  const int w    = threadIdx.x >> 6;
  const int lane = threadIdx.x & 63;
  const int ql = lane & 15, qd = lane >> 4;
  const int q0 = blockIdx.x * 64 + w * 16;

  const unsigned short* Qab = Qa + ((size_t)bh * Lq + q0) * 64;
  const unsigned short* Qbb = Qb + ((size_t)bh * Lq + q0) * 64;
  half8 aA[2], aB[2];
  for (int ks = 0; ks < 2; ++ks) {
    aA[ks] = *(const half8*)&Qab[ql * 64 + ks * 32 + qd * 8];
    aB[ks] = *(const half8*)&Qbb[ql * 64 + ks * 32 + qd * 8];
  }
  int mqr[4];
  for (int r = 0; r < 4; ++r) mqr[r] = mq[b * Lq + q0 + qd * 4 + r];

  float m[4], l[4];
  for (int r = 0; r < 4; ++r) { m[r] = -1e30f; l[r] = 0.0f; }
  f32x4 o[4];
  for (int nt = 0; nt < 4; ++nt) o[nt] = (f32x4)(0.0f);

  const unsigned short* Kb = K  + (size_t)bh * 1280 * 64;
  const unsigned short* Vb = VT + (size_t)bh * 64 * 1280;
  unsigned short* myP = Ps + w * 512;

  for (int k0 = 0; k0 < 1280; k0 += 32) {
    const bool vidp = (k0 < 1024);
    float sv[2][4];
    for (int sub = 0; sub < 2; ++sub) {
      const int kb = k0 + sub * 16;
      const half8 bf0 = *(const half8*)&Kb[(kb + ql) * 64 + qd * 8];
      const half8 bf1 = *(const half8*)&Kb[(kb + ql) * 64 + 32 + qd * 8];
      f32x4 S = (f32x4)(0.0f);
      if (vidp) { S = MFMA_F16(aA[0], bf0, S, 0, 0, 0); S = MFMA_F16(aA[1], bf1, S, 0, 0, 0); }
      else      { S = MFMA_F16(aB[0], bf0, S, 0, 0, 0); S = MFMA_F16(aB[1], bf1, S, 0, 0, 0); }
      const int kk = kb + ql;
      const int mk = vidp ? mkv[b * 1024 + kk] : mkt[b * 256 + kk - 1024];
      for (int r = 0; r < 4; ++r)
        sv[sub][r] = (mk && mqr[r]) ? S[r] : -10000.0f;
    }
    // block row-max: local pair-max, then merge across the 16 ql-lanes
    float bm[4];
    for (int r = 0; r < 4; ++r) bm[r] = fmaxf(sv[0][r], sv[1][r]);
    for (int off = 1; off < 16; off <<= 1)
      for (int r = 0; r < 4; ++r)
        bm[r] = fmaxf(bm[r], __shfl_xor(bm[r], off, 64));
    // online update
    float alpha[4];
    for (int r = 0; r < 4; ++r) {
      const float nm = fmaxf(m[r], bm[r]);
      alpha[r] = __expf(m[r] - nm);      // first block: exp(-1e30) = 0
      m[r] = nm;
    }
    for (int sub = 0; sub < 2; ++sub)
      for (int r = 0; r < 4; ++r) {
        const float p = __expf(sv[sub][r] - m[r]);   // arg <= 0 always
        sv[sub][r] = p;
        myP[(qd * 4 + r) * 32 + sub * 16 + ql] = f_to_f16u(p);
      }
    for (int r = 0; r < 4; ++r)
      l[r] = l[r] * alpha[r] + sv[0][r] + sv[1][r];
    for (int nt = 0; nt < 4; ++nt)
      for (int r = 0; r < 4; ++r) o[nt][r] *= alpha[r];

    __syncthreads();   // P C-layout writes visible before A-layout reads
    const half8 pA = *(const half8*)&myP[ql * 32 + qd * 8];
    for (int nt = 0; nt < 4; ++nt) {
      const half8 vf = *(const half8*)&Vb[(nt * 16 + ql) * 1280 + k0 + qd * 8];
      o[nt] = MFMA_F16(pA, vf, o[nt], 0, 0, 0);
    }
    __syncthreads();   // reads done before next iteration overwrites
  }

  // merge partial l across the 16 ql-lanes (all lanes share m[r] already)
  for (int off = 1; off < 16; off <<= 1)
    for (int r = 0; r < 4; ++r)
      l[r] += __shfl_xor(l[r], off, 64);

  for (int nt = 0; nt < 4; ++nt) {
    const int dh = nt * 16 + ql;
    for (int r = 0; r < 4; ++r) {
      const int q = q0 + qd * 4 + r;
      const size_t idx = ((size_t)(b * Lq + q)) * 1024 + h * 64 + dh;
      out[idx] = o[nt][r] * 0.125f / l[r];   // l >= 1 always
    }
  }
}

// ---------------------------------------------------------------------------
extern "C" void kernel_launch(void* const* d_in, const int* in_sizes, int n_in,
                              void* d_out, int out_size, void* d_ws, size_t ws_size,
                              hipStream_t stream) {
  const float* vid   = (const float*)d_in[0];
  const int*   vmask = (const int*)d_in[1];
  const float* txt   = (const float*)d_in[2];
  const int*   tmask = (const int*)d_in[3];
  const float* W_v2v = (const float*)d_in[4];
  const float* b_v2v = (const float*)d_in[5];
  const float* W_t2v = (const float*)d_in[6];
  const float* b_t2v = (const float*)d_in[7];
  const float* W_v2t = (const float*)d_in[8];
  const float* b_v2t = (const float*)d_in[9];
  const float* W_t2t = (const float*)d_in[10];
  const float* b_t2t = (const float*)d_in[11];

  const int DD = 1024 * 1024, Dm = 1024;

  unsigned short* ws = (unsigned short*)d_ws;
  unsigned short* Qa_v = ws;                       // 4,194,304 elems (f16)
  unsigned short* Qb_v = ws + 4194304;             // 4,194,304
  unsigned short* K_v  = ws + 8388608;             // 5,242,880
  unsigned short* V_vT = ws + 13631488;            // 5,242,880
  unsigned short* Qa_t = ws + 18874368;            // 1,048,576
  unsigned short* Qb_t = ws + 19922944;            // 1,048,576
  unsigned short* K_t  = ws + 20971520;            // 5,242,880
  unsigned short* V_tT = ws + 26214400;            // 5,242,880  (end 31,457,280)

  ProjArgs pa;
  auto set = [&](int i, const float* X, const float* W, const float* Bv,
                 unsigned short* dst, int M, int lxsh, int Ld, int soff, int mode) {
    pa.d[i] = ProjDesc{X, W, Bv, dst, M, lxsh, Ld, soff, mode};
  };
  //    idx  X    W              bias          dst    M     lxsh Ld    soff  mode
  set(0,  vid, W_v2v,          b_v2v,          Qa_v, 4096, 10, 1024, 0,    0);
  set(1,  vid, W_v2v + DD,     b_v2v + Dm,     K_v,  4096, 10, 1280, 0,    0);
  set(2,  vid, W_v2v + 2 * DD, b_v2v + 2 * Dm, V_vT, 4096, 10, 1280, 0,    1);
  set(3,  vid, W_t2v,          b_t2v,          Qb_v, 4096, 10, 1024, 0,    0);
  set(4,  txt, W_t2v + DD,     b_t2v + Dm,     K_v,  1024, 8,  1280, 1024, 0);
  set(5,  txt, W_t2v + 2 * DD, b_t2v + 2 * Dm, V_vT, 1024, 8,  1280, 1024, 1);
  set(6,  txt, W_v2t,          b_v2t,          Qa_t, 1024, 8,  256,  0,    0);
  set(7,  vid, W_v2t + DD,     b_v2t + Dm,     K_t,  4096, 10, 1280, 0,    0);
  set(8,  vid, W_v2t + 2 * DD, b_v2t + 2 * Dm, V_tT, 4096, 10, 1280, 0,    1);
  set(9,  txt, W_t2t,          b_t2t,          Qb_t, 1024, 8,  256,  0,    0);
  set(10, txt, W_t2t + DD,     b_t2t + Dm,     K_t,  1024, 8,  1280, 1024, 0);
  set(11, txt, W_t2t + 2 * DD, b_t2t + 2 * Dm, V_tT, 1024, 8,  1280, 1024, 1);

  proj_gemm<<<dim3(8, 32, 12), dim3(256), 0, stream>>>(pa);

  float* out_v = (float*)d_out;
  float* out_t = out_v + 4 * 1024 * 1024;
  attn_flash<<<dim3(16, 64), dim3(256), 0, stream>>>(
      Qa_v, Qb_v, K_v, V_vT, vmask, vmask, tmask, out_v, 1024);
  attn_flash<<<dim3(4, 64), dim3(256), 0, stream>>>(
      Qa_t, Qb_t, K_t, V_tT, tmask, vmask, tmask, out_t, 256);
}

// Round 6
// 452.467 us; speedup vs baseline: 2.7456x; 1.1732x over previous
//
#include <hip/hip_runtime.h>

// ---------------------------------------------------------------------------
// SegFormerXAttention on MI355X (gfx950)
//  B=4, Lv=1024, Lt=256, D=1024, H=16, DH=64, L=Lv+Lt=1280
//  fp32 in/out, int32 masks (verified r3/r5, absmax 3.9e-3).
//  r6: (1) fp32->fp16 pre-pass for X and W; proj GEMM in pure fp16 (m97
//      structure: global_load_lds 16B staging, 1x ds_read_b128/frag, no cvt
//      in K-loop). r5 counters showed 2x b128 + 8 cvt per frag = LDS-bound.
//      Guarded by ws_size (needs ~94 MB) with r5 fp32-GEMM fallback.
//      (2) attn: wave-private P tile -> barriers removed (s_waitcnt only),
//      v/t sides merged into one launch.
// ---------------------------------------------------------------------------

typedef __attribute__((ext_vector_type(8))) _Float16  half8;    // 8 x f16
typedef __attribute__((ext_vector_type(4))) float     f32x4;
typedef __attribute__((ext_vector_type(4))) unsigned int uint4v;

#define MFMA_F16  __builtin_amdgcn_mfma_f32_16x16x32_f16

static __device__ __forceinline__ unsigned short f_to_f16u(float f) {
  _Float16 h = (_Float16)f;
  return __builtin_bit_cast(unsigned short, h);
}

#define GLOAD_LDS16(g, l)                                            \
  __builtin_amdgcn_global_load_lds(                                  \
      (const __attribute__((address_space(1))) void*)(g),            \
      (__attribute__((address_space(3))) void*)(l), 16, 0, 0)

// ---------------------------------------------------------------------------
// Pre-pass: fp32 -> fp16 elementwise (16B loads x2 -> 16B store)
// ---------------------------------------------------------------------------
struct CvtDesc { const float* src; unsigned short* dst; int n8; };
struct CvtArgs { CvtDesc d[14]; };

__global__ __launch_bounds__(256) void cvt_fp16(CvtArgs ca) {
  const CvtDesc dd = ca.d[blockIdx.y];
  const int stride = gridDim.x * blockDim.x;
  for (int i = blockIdx.x * blockDim.x + threadIdx.x; i < dd.n8; i += stride) {
    const f32x4 a = ((const f32x4*)dd.src)[i * 2];
    const f32x4 b = ((const f32x4*)dd.src)[i * 2 + 1];
    half8 h;
    h[0] = (_Float16)a[0]; h[1] = (_Float16)a[1];
    h[2] = (_Float16)a[2]; h[3] = (_Float16)a[3];
    h[4] = (_Float16)b[0]; h[5] = (_Float16)b[1];
    h[6] = (_Float16)b[2]; h[7] = (_Float16)b[3];
    ((half8*)dd.dst)[i] = h;
  }
}

// ---------------------------------------------------------------------------
// Shared epilogue math (both GEMM variants):
//   mode 0: dst[((b*16+h)*Ld + soff + l)*64 + dh]      (Q / K, seq-major)
//   mode 1: dst[((b*16+h)*64 + dh)*Ld + soff + l]      (V transposed)
// ---------------------------------------------------------------------------
struct ProjDescH {
  const unsigned short* X;
  const unsigned short* W;
  const float* Bv;
  unsigned short* dst;
  int M, lxsh, Ld, soff, mode;
};
struct ProjArgsH { ProjDescH d[12]; };

__global__ __launch_bounds__(256) void proj_gemm_h(ProjArgsH pa) {
  const ProjDescH dd = pa.d[blockIdx.z];
  const int m0 = blockIdx.y * 128;
  if (m0 >= dd.M) return;
  const int n0 = blockIdx.x * 128;

  // union: staging (2 x 8 KB fp16) / epilogue C-tile (128 x 136 halfs, 34 KB)
  __shared__ __align__(16) unsigned char smem[34816];
  unsigned short* As = (unsigned short*)smem;   // 128x32 fp16, chunk-swizzled
  unsigned short* Bs = As + 4096;
  unsigned short* Cs = (unsigned short*)smem;

  const int tid  = threadIdx.x;
  const int lane = tid & 63;
  const int w    = tid >> 6;
  const int wr   = (w >> 1) * 64;
  const int wc   = (w & 1) * 64;
  const int ql   = lane & 15;
  const int qd   = lane >> 4;

  f32x4 acc[4][4];
  for (int i = 0; i < 4; ++i)
    for (int j = 0; j < 4; ++j) acc[i][j] = (f32x4)(0.0f);

  const unsigned short* Xg = dd.X + (size_t)m0 * 1024;
  const unsigned short* Wg = dd.W + (size_t)n0 * 1024;

  for (int k0 = 0; k0 < 1024; k0 += 32) {
    __syncthreads();
    // stage 128x32 fp16: 512 chunks of 16B (8 halfs); 2/thread/buffer;
    // global chunk index swizzled by row so fragment reads spread banks
    for (int half = 0; half < 2; ++half) {
      const int cb  = w * 128 + half * 64;       // wave-uniform chunk base
      const int c   = cb + lane;
      const int row = c >> 2;
      const int kcg = (c & 3) ^ (row & 3);
      GLOAD_LDS16(Xg + row * 1024 + k0 + kcg * 8, As + cb * 8);
      GLOAD_LDS16(Wg + row * 1024 + k0 + kcg * 8, Bs + cb * 8);
    }
    __syncthreads();

    half8 af[4], bf[4];
    for (int mt = 0; mt < 4; ++mt) {
      const int row = wr + mt * 16 + ql;
      af[mt] = *(const half8*)&As[row * 32 + ((qd ^ (row & 3)) << 3)];
    }
    for (int nt = 0; nt < 4; ++nt) {
      const int row = wc + nt * 16 + ql;
      bf[nt] = *(const half8*)&Bs[row * 32 + ((qd ^ (row & 3)) << 3)];
    }
    for (int mt = 0; mt < 4; ++mt)
      for (int nt = 0; nt < 4; ++nt)
        acc[mt][nt] = MFMA_F16(af[mt], bf[nt], acc[mt][nt], 0, 0, 0);
  }

  float bv[4];
  for (int nt = 0; nt < 4; ++nt)
    bv[nt] = dd.Bv[n0 + wc + nt * 16 + ql];

  __syncthreads();

  for (int mt = 0; mt < 4; ++mt) {
    for (int nt = 0; nt < 4; ++nt) {
      const int nl = wc + nt * 16 + ql;
      for (int r = 0; r < 4; ++r) {
        const int ml = wr + mt * 16 + qd * 4 + r;
        const int row = dd.mode == 0 ? ml : nl;
        const int col = dd.mode == 0 ? nl : ml;
        const float v = acc[mt][nt][r] + bv[nt];
        Cs[row * 136 + (((col >> 3) ^ (row & 7)) << 3) + (col & 7)] = f_to_f16u(v);
      }
    }
  }
  __syncthreads();

  const int b    = m0 >> dd.lxsh;
  const int l0   = m0 & ((1 << dd.lxsh) - 1);
  const int h0   = n0 >> 6;
  const int bh0  = b * 16 + h0;
  for (int i = 0; i < 8; ++i) {
    const int c     = i * 256 + tid;
    const int major = c >> 4;
    const int kc    = c & 15;
    const uint4v val =
        *(const uint4v*)&Cs[major * 136 + ((kc ^ (major & 7)) << 3)];
    size_t el;
    if (dd.mode == 0) {
      el = ((size_t)(bh0 + (kc >> 3)) * dd.Ld + dd.soff + l0 + major) * 64 +
           (kc & 7) * 8;
    } else {
      const int h  = h0 + (major >> 6);
      const int dh = major & 63;
      el = ((size_t)(b * 16 + h) * 64 + dh) * (size_t)dd.Ld + dd.soff + l0 + kc * 8;
    }
    *(uint4v*)(dd.dst + el) = val;
  }
}

// ---------------------------------------------------------------------------
// Fallback fp32-input GEMM (round-5 version) for small ws_size
// ---------------------------------------------------------------------------
struct ProjDesc {
  const float* X;
  const float* W;
  const float* Bv;
  unsigned short* dst;
  int M, lxsh, Ld, soff, mode;
};
struct ProjArgs { ProjDesc d[12]; };

static __device__ __forceinline__ half8 cvt8sw(const float* base, int row, int g0) {
  const int sw = row & 7;
  const f32x4 a = *(const f32x4*)(base + (row * 8 + (g0 ^ sw)) * 4);
  const f32x4 b = *(const f32x4*)(base + (row * 8 + ((g0 + 1) ^ sw)) * 4);
  half8 h;
  h[0] = (_Float16)a[0]; h[1] = (_Float16)a[1];
  h[2] = (_Float16)a[2]; h[3] = (_Float16)a[3];
  h[4] = (_Float16)b[0]; h[5] = (_Float16)b[1];
  h[6] = (_Float16)b[2]; h[7] = (_Float16)b[3];
  return h;
}

__global__ __launch_bounds__(256) void proj_gemm_f32(ProjArgs pa) {
  const ProjDesc dd = pa.d[blockIdx.z];
  const int m0 = blockIdx.y * 128;
  if (m0 >= dd.M) return;
  const int n0 = blockIdx.x * 128;

  __shared__ __align__(16) unsigned char smem[34816];
  float* As = (float*)smem;
  float* Bs = As + 4096;
  unsigned short* Cs = (unsigned short*)smem;

  const int tid  = threadIdx.x;
  const int lane = tid & 63;
  const int w    = tid >> 6;
  const int wr   = (w >> 1) * 64;
  const int wc   = (w & 1) * 64;
  const int ql   = lane & 15;
  const int qd   = lane >> 4;

  f32x4 acc[4][4];
  for (int i = 0; i < 4; ++i)
    for (int j = 0; j < 4; ++j) acc[i][j] = (f32x4)(0.0f);

  const float* Xg = dd.X + (size_t)m0 * 1024;
  const float* Wg = dd.W + (size_t)n0 * 1024;

  for (int k0 = 0; k0 < 1024; k0 += 32) {
    __syncthreads();
    for (int j = 0; j < 4; ++j) {
      const int cb  = (j * 4 + w) * 64;
      const int c   = cb + lane;
      const int row = c >> 3;
      const int kcg = (c & 7) ^ (row & 7);
      GLOAD_LDS16(Xg + row * 1024 + k0 + kcg * 4, As + cb * 4);
      GLOAD_LDS16(Wg + row * 1024 + k0 + kcg * 4, Bs + cb * 4);
    }
    __syncthreads();

    half8 af[4], bf[4];
    for (int mt = 0; mt < 4; ++mt)
      af[mt] = cvt8sw(As, wr + mt * 16 + ql, qd * 2);
    for (int nt = 0; nt < 4; ++nt)
      bf[nt] = cvt8sw(Bs, wc + nt * 16 + ql, qd * 2);
    for (int mt = 0; mt < 4; ++mt)
      for (int nt = 0; nt < 4; ++nt)
        acc[mt][nt] = MFMA_F16(af[mt], bf[nt], acc[mt][nt], 0, 0, 0);
  }

  float bv[4];
  for (int nt = 0; nt < 4; ++nt)
    bv[nt] = dd.Bv[n0 + wc + nt * 16 + ql];

  __syncthreads();

  for (int mt = 0; mt < 4; ++mt) {
    for (int nt = 0; nt < 4; ++nt) {
      const int nl = wc + nt * 16 + ql;
      for (int r = 0; r < 4; ++r) {
        const int ml = wr + mt * 16 + qd * 4 + r;
        const int row = dd.mode == 0 ? ml : nl;
        const int col = dd.mode == 0 ? nl : ml;
        const float v = acc[mt][nt][r] + bv[nt];
        Cs[row * 136 + (((col >> 3) ^ (row & 7)) << 3) + (col & 7)] = f_to_f16u(v);
      }
    }
  }
  __syncthreads();

  const int b    = m0 >> dd.lxsh;
  const int l0   = m0 & ((1 << dd.lxsh) - 1);
  const int h0   = n0 >> 6;
  const int bh0  = b * 16 + h0;
  for (int i = 0; i < 8; ++i) {
    const int c     = i * 256 + tid;
    const int major = c >> 4;
    const int kc    = c & 15;
    const uint4v val =
        *(const uint4v*)&Cs[major * 136 + ((kc ^ (major & 7)) << 3)];
    size_t el;
    if (dd.mode == 0) {
      el = ((size_t)(bh0 + (kc >> 3)) * dd.Ld + dd.soff + l0 + major) * 64 +
           (kc & 7) * 8;
    } else {
      const int h  = h0 + (major >> 6);
      const int dh = major & 63;
      el = ((size_t)(b * 16 + h) * 64 + dh) * (size_t)dd.Ld + dd.soff + l0 + kc * 8;
    }
    *(uint4v*)(dd.dst + el) = val;
  }
}

// ---------------------------------------------------------------------------
// Merged single-pass flash attention (v side: blockIdx.x 0..15, t: 16..19).
//  Per wave: 16 query rows; P tile is WAVE-PRIVATE LDS -> no __syncthreads,
//  only s_waitcnt lgkmcnt(0) between C-layout write and A-layout read
//  (per-wave DS pipeline is in-order).
// ---------------------------------------------------------------------------
__global__ __launch_bounds__(256) void attn_flash2(
    const unsigned short* __restrict__ Qa_v, const unsigned short* __restrict__ Qb_v,
    const unsigned short* __restrict__ K_v,  const unsigned short* __restrict__ V_vT,
    const unsigned short* __restrict__ Qa_t, const unsigned short* __restrict__ Qb_t,
    const unsigned short* __restrict__ K_t,  const unsigned short* __restrict__ V_tT,
    const int* __restrict__ vmask, const int* __restrict__ tmask,
    float* __restrict__ out_v, float* __restrict__ out_t) {
  __shared__ __align__(16) unsigned short Ps[4 * 512];

  const bool vside = blockIdx.x < 16;
  const int  qb    = vside ? blockIdx.x : blockIdx.x - 16;
  const int  Lq    = vside ? 1024 : 256;
  const unsigned short* Qa = vside ? Qa_v : Qa_t;
  const unsigned short* Qb = vside ? Qb_v : Qb_t;
  const unsigned short* K  = vside ? K_v  : K_t;
  const unsigned short* VT = vside ? V_vT : V_tT;
  const int* mq = vside ? vmask : tmask;
  float*     out = vside ? out_v : out_t;

  const int bh = blockIdx.y;
  const int b  = bh >> 4;
  const int h  = bh & 15;
  const int w    = threadIdx.x >> 6;
  const int lane = threadIdx.x & 63;
  const int ql = lane & 15, qd = lane >> 4;
  const int q0 = qb * 64 + w * 16;

  const unsigned short* Qab = Qa + ((size_t)bh * Lq + q0) * 64;
  const unsigned short* Qbb = Qb + ((size_t)bh * Lq + q0) * 64;
  half8 aA[2], aB[2];
  for (int ks = 0; ks < 2; ++ks) {
    aA[ks] = *(const half8*)&Qab[ql * 64 + ks * 32 + qd * 8];
    aB[ks] = *(const half8*)&Qbb[ql * 64 + ks * 32 + qd * 8];
  }
  int mqr[4];
  for (int r = 0; r < 4; ++r) mqr[r] = mq[b * Lq + q0 + qd * 4 + r];

  float m[4], l[4];
  for (int r = 0; r < 4; ++r) { m[r] = -1e30f; l[r] = 0.0f; }
  f32x4 o[4];
  for (int nt = 0; nt < 4; ++nt) o[nt] = (f32x4)(0.0f);

  const unsigned short* Kb = K  + (size_t)bh * 1280 * 64;
  const unsigned short* Vb = VT + (size_t)bh * 64 * 1280;
  unsigned short* myP = Ps + w * 512;

  for (int k0 = 0; k0 < 1280; k0 += 32) {
    const bool vidp = (k0 < 1024);
    float sv[2][4];
    for (int sub = 0; sub < 2; ++sub) {
      const int kb = k0 + sub * 16;
      const half8 bf0 = *(const half8*)&Kb[(kb + ql) * 64 + qd * 8];
      const half8 bf1 = *(const half8*)&Kb[(kb + ql) * 64 + 32 + qd * 8];
      f32x4 S = (f32x4)(0.0f);
      if (vidp) { S = MFMA_F16(aA[0], bf0, S, 0, 0, 0); S = MFMA_F16(aA[1], bf1, S, 0, 0, 0); }
      else      { S = MFMA_F16(aB[0], bf0, S, 0, 0, 0); S = MFMA_F16(aB[1], bf1, S, 0, 0, 0); }
      const int kk = kb + ql;
      const int mk = vidp ? vmask[b * 1024 + kk] : tmask[b * 256 + kk - 1024];
      for (int r = 0; r < 4; ++r)
        sv[sub][r] = (mk && mqr[r]) ? S[r] : -10000.0f;
    }
    float bm[4];
    for (int r = 0; r < 4; ++r) bm[r] = fmaxf(sv[0][r], sv[1][r]);
    for (int off = 1; off < 16; off <<= 1)
      for (int r = 0; r < 4; ++r)
        bm[r] = fmaxf(bm[r], __shfl_xor(bm[r], off, 64));
    float alpha[4];
    for (int r = 0; r < 4; ++r) {
      const float nm = fmaxf(m[r], bm[r]);
      alpha[r] = __expf(m[r] - nm);
      m[r] = nm;
    }
    for (int sub = 0; sub < 2; ++sub)
      for (int r = 0; r < 4; ++r) {
        const float p = __expf(sv[sub][r] - m[r]);
        sv[sub][r] = p;
        myP[(qd * 4 + r) * 32 + sub * 16 + ql] = f_to_f16u(p);
      }
    for (int r = 0; r < 4; ++r)
      l[r] = l[r] * alpha[r] + sv[0][r] + sv[1][r];
    for (int nt = 0; nt < 4; ++nt)
      for (int r = 0; r < 4; ++r) o[nt][r] *= alpha[r];

    // wave-private P: DS pipeline is in-order per wave; just drain writes
    __asm__ volatile("s_waitcnt lgkmcnt(0)" ::: "memory");
    const half8 pA = *(const half8*)&myP[ql * 32 + qd * 8];
    for (int nt = 0; nt < 4; ++nt) {
      const half8 vf = *(const half8*)&Vb[(nt * 16 + ql) * 1280 + k0 + qd * 8];
      o[nt] = MFMA_F16(pA, vf, o[nt], 0, 0, 0);
    }
  }

  for (int off = 1; off < 16; off <<= 1)
    for (int r = 0; r < 4; ++r)
      l[r] += __shfl_xor(l[r], off, 64);

  for (int nt = 0; nt < 4; ++nt) {
    const int dh = nt * 16 + ql;
    for (int r = 0; r < 4; ++r) {
      const int q = q0 + qd * 4 + r;
      const size_t idx = ((size_t)(b * Lq + q)) * 1024 + h * 64 + dh;
      out[idx] = o[nt][r] * 0.125f / l[r];
    }
  }
}

// ---------------------------------------------------------------------------
extern "C" void kernel_launch(void* const* d_in, const int* in_sizes, int n_in,
                              void* d_out, int out_size, void* d_ws, size_t ws_size,
                              hipStream_t stream) {
  const float* vid   = (const float*)d_in[0];
  const int*   vmask = (const int*)d_in[1];
  const float* txt   = (const float*)d_in[2];
  const int*   tmask = (const int*)d_in[3];
  const float* Wsrc[4] = {(const float*)d_in[4], (const float*)d_in[6],
                          (const float*)d_in[8], (const float*)d_in[10]};
  const float* Bsrc[4] = {(const float*)d_in[5], (const float*)d_in[7],
                          (const float*)d_in[9], (const float*)d_in[11]};

  const int DD = 1024 * 1024, Dm = 1024, MEG = 1048576;

  unsigned short* ws = (unsigned short*)d_ws;
  unsigned short* Qa_v = ws;                       // 4,194,304 halfs
  unsigned short* Qb_v = ws + 4194304;
  unsigned short* K_v  = ws + 8388608;             // 5,242,880
  unsigned short* V_vT = ws + 13631488;
  unsigned short* Qa_t = ws + 18874368;            // 1,048,576
  unsigned short* Qb_t = ws + 19922944;
  unsigned short* K_t  = ws + 20971520;            // 5,242,880
  unsigned short* V_tT = ws + 26214400;            // end 31,457,280
  unsigned short* Xv_h = ws + 31457280;            // 4,194,304
  unsigned short* Xt_h = ws + 35651584;            // 1,048,576
  unsigned short* Wh   = ws + 36700160;            // 12 x 1,048,576 -> end 49,283,072

  const size_t need = (size_t)49283072 * 2;
  const bool use_h = ws_size >= need;

  if (use_h) {
    CvtArgs ca;
    ca.d[0] = CvtDesc{vid, Xv_h, 4194304 / 8};
    ca.d[1] = CvtDesc{txt, Xt_h, 1048576 / 8};
    for (int s = 0; s < 4; ++s)
      for (int j = 0; j < 3; ++j)
        ca.d[2 + s * 3 + j] = CvtDesc{Wsrc[s] + j * DD, Wh + (s * 3 + j) * MEG, DD / 8};
    cvt_fp16<<<dim3(256, 14), dim3(256), 0, stream>>>(ca);

    ProjArgsH pa;
    auto set = [&](int i, const unsigned short* X, int wi, const float* Bv,
                   unsigned short* dst, int M, int lxsh, int Ld, int soff, int mode) {
      pa.d[i] = ProjDescH{X, Wh + wi * MEG, Bv, dst, M, lxsh, Ld, soff, mode};
    };
    //    idx  X     Wi  bias          dst    M     lxsh Ld    soff  mode
    set(0,  Xv_h, 0,  Bsrc[0],          Qa_v, 4096, 10, 1024, 0,    0);
    set(1,  Xv_h, 1,  Bsrc[0] + Dm,     K_v,  4096, 10, 1280, 0,    0);
    set(2,  Xv_h, 2,  Bsrc[0] + 2 * Dm, V_vT, 4096, 10, 1280, 0,    1);
    set(3,  Xv_h, 3,  Bsrc[1],          Qb_v, 4096, 10, 1024, 0,    0);
    set(4,  Xt_h, 4,  Bsrc[1] + Dm,     K_v,  1024, 8,  1280, 1024, 0);
    set(5,  Xt_h, 5,  Bsrc[1] + 2 * Dm, V_vT, 1024, 8,  1280, 1024, 1);
    set(6,  Xt_h, 6,  Bsrc[2],          Qa_t, 1024, 8,  256,  0,    0);
    set(7,  Xv_h, 7,  Bsrc[2] + Dm,     K_t,  4096, 10, 1280, 0,    0);
    set(8,  Xv_h, 8,  Bsrc[2] + 2 * Dm, V_tT, 4096, 10, 1280, 0,    1);
    set(9,  Xt_h, 9,  Bsrc[3],          Qb_t, 1024, 8,  256,  0,    0);
    set(10, Xt_h, 10, Bsrc[3] + Dm,     K_t,  1024, 8,  1280, 1024, 0);
    set(11, Xt_h, 11, Bsrc[3] + 2 * Dm, V_tT, 1024, 8,  1280, 1024, 1);

    proj_gemm_h<<<dim3(8, 32, 12), dim3(256), 0, stream>>>(pa);
  } else {
    ProjArgs pa;
    auto set = [&](int i, const float* X, const float* W, const float* Bv,
                   unsigned short* dst, int M, int lxsh, int Ld, int soff, int mode) {
      pa.d[i] = ProjDesc{X, W, Bv, dst, M, lxsh, Ld, soff, mode};
    };
    set(0,  vid, Wsrc[0],          Bsrc[0],          Qa_v, 4096, 10, 1024, 0,    0);
    set(1,  vid, Wsrc[0] + DD,     Bsrc[0] + Dm,     K_v,  4096, 10, 1280, 0,    0);
    set(2,  vid, Wsrc[0] + 2 * DD, Bsrc[0] + 2 * Dm, V_vT, 4096, 10, 1280, 0,    1);
    set(3,  vid, Wsrc[1],          Bsrc[1],          Qb_v, 4096, 10, 1024, 0,    0);
    set(4,  txt, Wsrc[1] + DD,     Bsrc[1] + Dm,     K_v,  1024, 8,  1280, 1024, 0);
    set(5,  txt, Wsrc[1] + 2 * DD, Bsrc[1] + 2 * Dm, V_vT, 1024, 8,  1280, 1024, 1);
    set(6,  txt, Wsrc[2],          Bsrc[2],          Qa_t, 1024, 8,  256,  0,    0);
    set(7,  vid, Wsrc[2] + DD,     Bsrc[2] + Dm,     K_t,  4096, 10, 1280, 0,    0);
    set(8,  vid, Wsrc[2] + 2 * DD, Bsrc[2] + 2 * Dm, V_tT, 4096, 10, 1280, 0,    1);
    set(9,  txt, Wsrc[3],          Bsrc[3],          Qb_t, 1024, 8,  256,  0,    0);
    set(10, txt, Wsrc[3] + DD,     Bsrc[3] + Dm,     K_t,  1024, 8,  1280, 1024, 0);
    set(11, txt, Wsrc[3] + 2 * DD, Bsrc[3] + 2 * Dm, V_tT, 1024, 8,  1280, 1024, 1);

    proj_gemm_f32<<<dim3(8, 32, 12), dim3(256), 0, stream>>>(pa);
  }

  float* out_v = (float*)d_out;
  float* out_t = out_v + 4 * 1024 * 1024;
  attn_flash2<<<dim3(20, 64), dim3(256), 0, stream>>>(
      Qa_v, Qb_v, K_v, V_vT, Qa_t, Qb_t, K_t, V_tT,
      vmask, tmask, out_v, out_t);
}

// Round 7
// 407.377 us; speedup vs baseline: 3.0495x; 1.1107x over previous
//
#include <hip/hip_runtime.h>

// ---------------------------------------------------------------------------
// SegFormerXAttention on MI355X (gfx950)
//  B=4, Lv=1024, Lt=256, D=1024, H=16, DH=64, L=1280. fp32 in/out, int32 masks.
//  r7: attention restructured for latency (r6 counters: 255us, VALUBusy 27%,
//      MfmaUtil 4%, occupancy 32% -> dependency-chain bound, not throughput):
//      (1) split-K 4-way: block = 16 q-rows, 4 waves x 320 keys, LDS merge.
//          5120 blocks / 20480 waves (2.5x CU capacity), chain/wave 4x shorter.
//      (2) key mask folded into QK^T accumulator init via fp32 kbias[b][1280]
//          (0 / -10000); additive == reference replace-masking bitwise after
//          fp32 exp underflow; mq==0 uniform rows kept exact via mqr cndmask.
//      proj/cvt unchanged from r6.
// ---------------------------------------------------------------------------

typedef __attribute__((ext_vector_type(8))) _Float16  half8;    // 8 x f16
typedef __attribute__((ext_vector_type(4))) float     f32x4;
typedef __attribute__((ext_vector_type(4))) unsigned int uint4v;

#define MFMA_F16  __builtin_amdgcn_mfma_f32_16x16x32_f16

static __device__ __forceinline__ unsigned short f_to_f16u(float f) {
  _Float16 h = (_Float16)f;
  return __builtin_bit_cast(unsigned short, h);
}

#define GLOAD_LDS16(g, l)                                            \
  __builtin_amdgcn_global_load_lds(                                  \
      (const __attribute__((address_space(1))) void*)(g),            \
      (__attribute__((address_space(3))) void*)(l), 16, 0, 0)

// ---------------------------------------------------------------------------
// Pre-pass: fp32 -> fp16 elementwise
// ---------------------------------------------------------------------------
struct CvtDesc { const float* src; unsigned short* dst; int n8; };
struct CvtArgs { CvtDesc d[14]; };

__global__ __launch_bounds__(256) void cvt_fp16(CvtArgs ca) {
  const CvtDesc dd = ca.d[blockIdx.y];
  const int stride = gridDim.x * blockDim.x;
  for (int i = blockIdx.x * blockDim.x + threadIdx.x; i < dd.n8; i += stride) {
    const f32x4 a = ((const f32x4*)dd.src)[i * 2];
    const f32x4 b = ((const f32x4*)dd.src)[i * 2 + 1];
    half8 h;
    h[0] = (_Float16)a[0]; h[1] = (_Float16)a[1];
    h[2] = (_Float16)a[2]; h[3] = (_Float16)a[3];
    h[4] = (_Float16)b[0]; h[5] = (_Float16)b[1];
    h[6] = (_Float16)b[2]; h[7] = (_Float16)b[3];
    ((half8*)dd.dst)[i] = h;
  }
}

// key-mask bias: kb[b][k] = mask ? 0 : -10000   (runs AFTER proj: reuses
// the then-dead Xv_h workspace region)
__global__ __launch_bounds__(256) void make_kbias(
    const int* __restrict__ vmask, const int* __restrict__ tmask,
    float* __restrict__ kb) {
  const int b = blockIdx.y;
  const int k = blockIdx.x * 256 + threadIdx.x;
  if (k >= 1280) return;
  const int m = (k < 1024) ? vmask[b * 1024 + k] : tmask[b * 256 + k - 1024];
  kb[b * 1280 + k] = m ? 0.0f : -10000.0f;
}

// ---------------------------------------------------------------------------
// Projection GEMM (fp16 inputs) -- unchanged from r6
//   mode 0: dst[((b*16+h)*Ld + soff + l)*64 + dh]      (Q / K, seq-major)
//   mode 1: dst[((b*16+h)*64 + dh)*Ld + soff + l]      (V transposed)
// ---------------------------------------------------------------------------
struct ProjDescH {
  const unsigned short* X;
  const unsigned short* W;
  const float* Bv;
  unsigned short* dst;
  int M, lxsh, Ld, soff, mode;
};
struct ProjArgsH { ProjDescH d[12]; };

__global__ __launch_bounds__(256) void proj_gemm_h(ProjArgsH pa) {
  const ProjDescH dd = pa.d[blockIdx.z];
  const int m0 = blockIdx.y * 128;
  if (m0 >= dd.M) return;
  const int n0 = blockIdx.x * 128;

  __shared__ __align__(16) unsigned char smem[34816];
  unsigned short* As = (unsigned short*)smem;
  unsigned short* Bs = As + 4096;
  unsigned short* Cs = (unsigned short*)smem;

  const int tid  = threadIdx.x;
  const int lane = tid & 63;
  const int w    = tid >> 6;
  const int wr   = (w >> 1) * 64;
  const int wc   = (w & 1) * 64;
  const int ql   = lane & 15;
  const int qd   = lane >> 4;

  f32x4 acc[4][4];
  for (int i = 0; i < 4; ++i)
    for (int j = 0; j < 4; ++j) acc[i][j] = (f32x4)(0.0f);

  const unsigned short* Xg = dd.X + (size_t)m0 * 1024;
  const unsigned short* Wg = dd.W + (size_t)n0 * 1024;

  for (int k0 = 0; k0 < 1024; k0 += 32) {
    __syncthreads();
    for (int half = 0; half < 2; ++half) {
      const int cb  = w * 128 + half * 64;
      const int c   = cb + lane;
      const int row = c >> 2;
      const int kcg = (c & 3) ^ (row & 3);
      GLOAD_LDS16(Xg + row * 1024 + k0 + kcg * 8, As + cb * 8);
      GLOAD_LDS16(Wg + row * 1024 + k0 + kcg * 8, Bs + cb * 8);
    }
    __syncthreads();

    half8 af[4], bf[4];
    for (int mt = 0; mt < 4; ++mt) {
      const int row = wr + mt * 16 + ql;
      af[mt] = *(const half8*)&As[row * 32 + ((qd ^ (row & 3)) << 3)];
    }
    for (int nt = 0; nt < 4; ++nt) {
      const int row = wc + nt * 16 + ql;
      bf[nt] = *(const half8*)&Bs[row * 32 + ((qd ^ (row & 3)) << 3)];
    }
    for (int mt = 0; mt < 4; ++mt)
      for (int nt = 0; nt < 4; ++nt)
        acc[mt][nt] = MFMA_F16(af[mt], bf[nt], acc[mt][nt], 0, 0, 0);
  }

  float bv[4];
  for (int nt = 0; nt < 4; ++nt)
    bv[nt] = dd.Bv[n0 + wc + nt * 16 + ql];

  __syncthreads();

  for (int mt = 0; mt < 4; ++mt) {
    for (int nt = 0; nt < 4; ++nt) {
      const int nl = wc + nt * 16 + ql;
      for (int r = 0; r < 4; ++r) {
        const int ml = wr + mt * 16 + qd * 4 + r;
        const int row = dd.mode == 0 ? ml : nl;
        const int col = dd.mode == 0 ? nl : ml;
        const float v = acc[mt][nt][r] + bv[nt];
        Cs[row * 136 + (((col >> 3) ^ (row & 7)) << 3) + (col & 7)] = f_to_f16u(v);
      }
    }
  }
  __syncthreads();

  const int b    = m0 >> dd.lxsh;
  const int l0   = m0 & ((1 << dd.lxsh) - 1);
  const int h0   = n0 >> 6;
  const int bh0  = b * 16 + h0;
  for (int i = 0; i < 8; ++i) {
    const int c     = i * 256 + tid;
    const int major = c >> 4;
    const int kc    = c & 15;
    const uint4v val =
        *(const uint4v*)&Cs[major * 136 + ((kc ^ (major & 7)) << 3)];
    size_t el;
    if (dd.mode == 0) {
      el = ((size_t)(bh0 + (kc >> 3)) * dd.Ld + dd.soff + l0 + major) * 64 +
           (kc & 7) * 8;
    } else {
      const int h  = h0 + (major >> 6);
      const int dh = major & 63;
      el = ((size_t)(b * 16 + h) * 64 + dh) * (size_t)dd.Ld + dd.soff + l0 + kc * 8;
    }
    *(uint4v*)(dd.dst + el) = val;
  }
}

// ---------------------------------------------------------------------------
// Fallback fp32-input GEMM (r5 version) for small ws_size
// ---------------------------------------------------------------------------
struct ProjDesc {
  const float* X;
  const float* W;
  const float* Bv;
  unsigned short* dst;
  int M, lxsh, Ld, soff, mode;
};
struct ProjArgs { ProjDesc d[12]; };

static __device__ __forceinline__ half8 cvt8sw(const float* base, int row, int g0) {
  const int sw = row & 7;
  const f32x4 a = *(const f32x4*)(base + (row * 8 + (g0 ^ sw)) * 4);
  const f32x4 b = *(const f32x4*)(base + (row * 8 + ((g0 + 1) ^ sw)) * 4);
  half8 h;
  h[0] = (_Float16)a[0]; h[1] = (_Float16)a[1];
  h[2] = (_Float16)a[2]; h[3] = (_Float16)a[3];
  h[4] = (_Float16)b[0]; h[5] = (_Float16)b[1];
  h[6] = (_Float16)b[2]; h[7] = (_Float16)b[3];
  return h;
}

__global__ __launch_bounds__(256) void proj_gemm_f32(ProjArgs pa) {
  const ProjDesc dd = pa.d[blockIdx.z];
  const int m0 = blockIdx.y * 128;
  if (m0 >= dd.M) return;
  const int n0 = blockIdx.x * 128;

  __shared__ __align__(16) unsigned char smem[34816];
  float* As = (float*)smem;
  float* Bs = As + 4096;
  unsigned short* Cs = (unsigned short*)smem;

  const int tid  = threadIdx.x;
  const int lane = tid & 63;
  const int w    = tid >> 6;
  const int wr   = (w >> 1) * 64;
  const int wc   = (w & 1) * 64;
  const int ql   = lane & 15;
  const int qd   = lane >> 4;

  f32x4 acc[4][4];
  for (int i = 0; i < 4; ++i)
    for (int j = 0; j < 4; ++j) acc[i][j] = (f32x4)(0.0f);

  const float* Xg = dd.X + (size_t)m0 * 1024;
  const float* Wg = dd.W + (size_t)n0 * 1024;

  for (int k0 = 0; k0 < 1024; k0 += 32) {
    __syncthreads();
    for (int j = 0; j < 4; ++j) {
      const int cb  = (j * 4 + w) * 64;
      const int c   = cb + lane;
      const int row = c >> 3;
      const int kcg = (c & 7) ^ (row & 7);
      GLOAD_LDS16(Xg + row * 1024 + k0 + kcg * 4, As + cb * 4);
      GLOAD_LDS16(Wg + row * 1024 + k0 + kcg * 4, Bs + cb * 4);
    }
    __syncthreads();

    half8 af[4], bf[4];
    for (int mt = 0; mt < 4; ++mt)
      af[mt] = cvt8sw(As, wr + mt * 16 + ql, qd * 2);
    for (int nt = 0; nt < 4; ++nt)
      bf[nt] = cvt8sw(Bs, wc + nt * 16 + ql, qd * 2);
    for (int mt = 0; mt < 4; ++mt)
      for (int nt = 0; nt < 4; ++nt)
        acc[mt][nt] = MFMA_F16(af[mt], bf[nt], acc[mt][nt], 0, 0, 0);
  }

  float bv[4];
  for (int nt = 0; nt < 4; ++nt)
    bv[nt] = dd.Bv[n0 + wc + nt * 16 + ql];

  __syncthreads();

  for (int mt = 0; mt < 4; ++mt) {
    for (int nt = 0; nt < 4; ++nt) {
      const int nl = wc + nt * 16 + ql;
      for (int r = 0; r < 4; ++r) {
        const int ml = wr + mt * 16 + qd * 4 + r;
        const int row = dd.mode == 0 ? ml : nl;
        const int col = dd.mode == 0 ? nl : ml;
        const float v = acc[mt][nt][r] + bv[nt];
        Cs[row * 136 + (((col >> 3) ^ (row & 7)) << 3) + (col & 7)] = f_to_f16u(v);
      }
    }
  }
  __syncthreads();

  const int b    = m0 >> dd.lxsh;
  const int l0   = m0 & ((1 << dd.lxsh) - 1);
  const int h0   = n0 >> 6;
  const int bh0  = b * 16 + h0;
  for (int i = 0; i < 8; ++i) {
    const int c     = i * 256 + tid;
    const int major = c >> 4;
    const int kc    = c & 15;
    const uint4v val =
        *(const uint4v*)&Cs[major * 136 + ((kc ^ (major & 7)) << 3)];
    size_t el;
    if (dd.mode == 0) {
      el = ((size_t)(bh0 + (kc >> 3)) * dd.Ld + dd.soff + l0 + major) * 64 +
           (kc & 7) * 8;
    } else {
      const int h  = h0 + (major >> 6);
      const int dh = major & 63;
      el = ((size_t)(b * 16 + h) * 64 + dh) * (size_t)dd.Ld + dd.soff + l0 + kc * 8;
    }
    *(uint4v*)(dd.dst + el) = val;
  }
}

// ---------------------------------------------------------------------------
// Split-K flash attention. Block = 16 q-rows (x<64: v-side qb, x>=64: t-side).
//  Wave w handles keys [w*320, w*320+320). Per 32-key block: QK^T MFMA with
//  accumulator initialized to kbias (masked keys start at S-10000 -> exp
//  underflows to exactly 0, bitwise-equal to reference replace-masking);
//  per-row mq==0 handled by in-register cndmask (uniform row stays exact).
//  Wave-private P tile: no barriers in the loop. End: (m,l,o) merged across
//  the 4 waves via LDS, out = 0.125 * o* / l*.
// ---------------------------------------------------------------------------
__global__ __launch_bounds__(256) void attn_flash3(
    const unsigned short* __restrict__ Qa_v, const unsigned short* __restrict__ Qb_v,
    const unsigned short* __restrict__ K_v,  const unsigned short* __restrict__ V_vT,
    const unsigned short* __restrict__ Qa_t, const unsigned short* __restrict__ Qb_t,
    const unsigned short* __restrict__ K_t,  const unsigned short* __restrict__ V_tT,
    const int* __restrict__ vmask, const int* __restrict__ tmask,
    const float* __restrict__ kbias,
    float* __restrict__ out_v, float* __restrict__ out_t) {
  // union: wave-private P tiles (4x512 halfs = 4KB) / end merge buffers
  __shared__ __align__(16) unsigned char smem[17920];
  unsigned short* Ps  = (unsigned short*)smem;
  float*          oM  = (float*)smem;        // o[w][q][68]  (4*16*68 floats)
  float*          mlM = oM + 4352;           // ml[w][{m,l}][16]

  const bool vside = blockIdx.x < 64;
  const int  qb    = vside ? blockIdx.x : blockIdx.x - 64;
  const int  Lq    = vside ? 1024 : 256;
  const unsigned short* Qa = vside ? Qa_v : Qa_t;
  const unsigned short* Qb = vside ? Qb_v : Qb_t;
  const unsigned short* K  = vside ? K_v  : K_t;
  const unsigned short* VT = vside ? V_vT : V_tT;
  const int* mq  = vside ? vmask : tmask;
  float*     out = vside ? out_v : out_t;

  const int bh = blockIdx.y;
  const int b  = bh >> 4;
  const int h  = bh & 15;
  const int w    = threadIdx.x >> 6;
  const int lane = threadIdx.x & 63;
  const int ql = lane & 15, qd = lane >> 4;
  const int q0 = qb * 16;

  // 16 shared Q rows (same for all 4 waves)
  const unsigned short* Qab = Qa + ((size_t)bh * Lq + q0) * 64;
  const unsigned short* Qbb = Qb + ((size_t)bh * Lq + q0) * 64;
  half8 aA[2], aB[2];
  for (int ks = 0; ks < 2; ++ks) {
    aA[ks] = *(const half8*)&Qab[ql * 64 + ks * 32 + qd * 8];
    aB[ks] = *(const half8*)&Qbb[ql * 64 + ks * 32 + qd * 8];
  }
  int mqr[4];
  for (int r = 0; r < 4; ++r) mqr[r] = mq[b * Lq + q0 + qd * 4 + r];

  float m[4], l[4];
  for (int r = 0; r < 4; ++r) { m[r] = -1e30f; l[r] = 0.0f; }
  f32x4 o[4];
  for (int nt = 0; nt < 4; ++nt) o[nt] = (f32x4)(0.0f);

  const unsigned short* Kb = K  + (size_t)bh * 1280 * 64;
  const unsigned short* Vb = VT + (size_t)bh * 64 * 1280;
  const float* kbb = kbias + b * 1280;
  unsigned short* myP = Ps + w * 512;

  const int kw0 = w * 320;
  for (int k0 = kw0; k0 < kw0 + 320; k0 += 32) {
    const bool vidp = (k0 < 1024);
    float sv[2][4];
    for (int sub = 0; sub < 2; ++sub) {
      const int kb = k0 + sub * 16;
      const float kbv = kbb[kb + ql];              // masked-key bias (0/-1e4)
      const half8 bf0 = *(const half8*)&Kb[(kb + ql) * 64 + qd * 8];
      const half8 bf1 = *(const half8*)&Kb[(kb + ql) * 64 + 32 + qd * 8];
      f32x4 S;
      S[0] = kbv; S[1] = kbv; S[2] = kbv; S[3] = kbv;
      if (vidp) { S = MFMA_F16(aA[0], bf0, S, 0, 0, 0); S = MFMA_F16(aA[1], bf1, S, 0, 0, 0); }
      else      { S = MFMA_F16(aB[0], bf0, S, 0, 0, 0); S = MFMA_F16(aB[1], bf1, S, 0, 0, 0); }
      for (int r = 0; r < 4; ++r)
        sv[sub][r] = mqr[r] ? S[r] : -10000.0f;
    }
    float bm[4];
    for (int r = 0; r < 4; ++r) bm[r] = fmaxf(sv[0][r], sv[1][r]);
    for (int off = 1; off < 16; off <<= 1)
      for (int r = 0; r < 4; ++r)
        bm[r] = fmaxf(bm[r], __shfl_xor(bm[r], off, 64));
    float alpha[4];
    for (int r = 0; r < 4; ++r) {
      const float nm = fmaxf(m[r], bm[r]);
      alpha[r] = __expf(m[r] - nm);
      m[r] = nm;
    }
    for (int sub = 0; sub < 2; ++sub)
      for (int r = 0; r < 4; ++r) {
        const float p = __expf(sv[sub][r] - m[r]);
        sv[sub][r] = p;
        myP[(qd * 4 + r) * 32 + sub * 16 + ql] = f_to_f16u(p);
      }
    for (int r = 0; r < 4; ++r)
      l[r] = l[r] * alpha[r] + sv[0][r] + sv[1][r];
    for (int nt = 0; nt < 4; ++nt)
      for (int r = 0; r < 4; ++r) o[nt][r] *= alpha[r];

    __asm__ volatile("s_waitcnt lgkmcnt(0)" ::: "memory");
    const half8 pA = *(const half8*)&myP[ql * 32 + qd * 8];
    for (int nt = 0; nt < 4; ++nt) {
      const half8 vf = *(const half8*)&Vb[(nt * 16 + ql) * 1280 + k0 + qd * 8];
      o[nt] = MFMA_F16(pA, vf, o[nt], 0, 0, 0);
    }
  }

  // per-wave l: sum partials across the 16 ql lanes (m already merged)
  for (int off = 1; off < 16; off <<= 1)
    for (int r = 0; r < 4; ++r)
      l[r] += __shfl_xor(l[r], off, 64);

  __syncthreads();   // all waves done with Ps before merge buffers overwrite
  for (int nt = 0; nt < 4; ++nt)
    for (int r = 0; r < 4; ++r)
      oM[w * 1088 + (qd * 4 + r) * 68 + nt * 16 + ql] = o[nt][r];
  if (ql == 0)
    for (int r = 0; r < 4; ++r) {
      mlM[w * 32 + qd * 4 + r]      = m[r];
      mlM[w * 32 + 16 + qd * 4 + r] = l[r];
    }
  __syncthreads();

  // merge: thread t handles q = t>>4, d = (t&15)*4 .. +3
  const int q  = threadIdx.x >> 4;
  const int d0 = (threadIdx.x & 15) * 4;
  float mw[4], lw[4];
  for (int w2 = 0; w2 < 4; ++w2) {
    mw[w2] = mlM[w2 * 32 + q];
    lw[w2] = mlM[w2 * 32 + 16 + q];
  }
  float ms = fmaxf(fmaxf(mw[0], mw[1]), fmaxf(mw[2], mw[3]));
  float fw[4], ls = 0.0f;
  for (int w2 = 0; w2 < 4; ++w2) {
    fw[w2] = __expf(mw[w2] - ms);
    ls += fw[w2] * lw[w2];
  }
  const float inv = 0.125f / ls;   // ls >= 1 always
  f32x4 res;
  for (int j = 0; j < 4; ++j) {
    float a = 0.0f;
    for (int w2 = 0; w2 < 4; ++w2)
      a += fw[w2] * oM[w2 * 1088 + q * 68 + d0 + j];
    res[j] = a * inv;
  }
  *(f32x4*)(out + ((size_t)(b * Lq + q0 + q)) * 1024 + h * 64 + d0) = res;
}

// ---------------------------------------------------------------------------
extern "C" void kernel_launch(void* const* d_in, const int* in_sizes, int n_in,
                              void* d_out, int out_size, void* d_ws, size_t ws_size,
                              hipStream_t stream) {
  const float* vid   = (const float*)d_in[0];
  const int*   vmask = (const int*)d_in[1];
  const float* txt   = (const float*)d_in[2];
  const int*   tmask = (const int*)d_in[3];
  const float* Wsrc[4] = {(const float*)d_in[4], (const float*)d_in[6],
                          (const float*)d_in[8], (const float*)d_in[10]};
  const float* Bsrc[4] = {(const float*)d_in[5], (const float*)d_in[7],
                          (const float*)d_in[9], (const float*)d_in[11]};

  const int DD = 1024 * 1024, Dm = 1024, MEG = 1048576;

  unsigned short* ws = (unsigned short*)d_ws;
  unsigned short* Qa_v = ws;                       // 4,194,304 halfs
  unsigned short* Qb_v = ws + 4194304;
  unsigned short* K_v  = ws + 8388608;             // 5,242,880
  unsigned short* V_vT = ws + 13631488;
  unsigned short* Qa_t = ws + 18874368;            // 1,048,576
  unsigned short* Qb_t = ws + 19922944;
  unsigned short* K_t  = ws + 20971520;            // 5,242,880
  unsigned short* V_tT = ws + 26214400;            // end 31,457,280
  unsigned short* Xv_h = ws + 31457280;            // 4,194,304 (dead after proj)
  unsigned short* Xt_h = ws + 35651584;            // 1,048,576
  unsigned short* Wh   = ws + 36700160;            // 12 MEG -> end 49,283,072
  float* kbias = (float*)(ws + 31457280);          // 5120 f32, reuses Xv_h
                                                   // region AFTER proj is done

  const size_t need = (size_t)49283072 * 2;
  const bool use_h = ws_size >= need;

  if (use_h) {
    CvtArgs ca;
    ca.d[0] = CvtDesc{vid, Xv_h, 4194304 / 8};
    ca.d[1] = CvtDesc{txt, Xt_h, 1048576 / 8};
    for (int s = 0; s < 4; ++s)
      for (int j = 0; j < 3; ++j)
        ca.d[2 + s * 3 + j] = CvtDesc{Wsrc[s] + j * DD, Wh + (s * 3 + j) * MEG, DD / 8};
    cvt_fp16<<<dim3(256, 14), dim3(256), 0, stream>>>(ca);

    ProjArgsH pa;
    auto set = [&](int i, const unsigned short* X, int wi, const float* Bv,
                   unsigned short* dst, int M, int lxsh, int Ld, int soff, int mode) {
      pa.d[i] = ProjDescH{X, Wh + wi * MEG, Bv, dst, M, lxsh, Ld, soff, mode};
    };
    set(0,  Xv_h, 0,  Bsrc[0],          Qa_v, 4096, 10, 1024, 0,    0);
    set(1,  Xv_h, 1,  Bsrc[0] + Dm,     K_v,  4096, 10, 1280, 0,    0);
    set(2,  Xv_h, 2,  Bsrc[0] + 2 * Dm, V_vT, 4096, 10, 1280, 0,    1);
    set(3,  Xv_h, 3,  Bsrc[1],          Qb_v, 4096, 10, 1024, 0,    0);
    set(4,  Xt_h, 4,  Bsrc[1] + Dm,     K_v,  1024, 8,  1280, 1024, 0);
    set(5,  Xt_h, 5,  Bsrc[1] + 2 * Dm, V_vT, 1024, 8,  1280, 1024, 1);
    set(6,  Xt_h, 6,  Bsrc[2],          Qa_t, 1024, 8,  256,  0,    0);
    set(7,  Xv_h, 7,  Bsrc[2] + Dm,     K_t,  4096, 10, 1280, 0,    0);
    set(8,  Xv_h, 8,  Bsrc[2] + 2 * Dm, V_tT, 4096, 10, 1280, 0,    1);
    set(9,  Xt_h, 9,  Bsrc[3],          Qb_t, 1024, 8,  256,  0,    0);
    set(10, Xt_h, 10, Bsrc[3] + Dm,     K_t,  1024, 8,  1280, 1024, 0);
    set(11, Xt_h, 11, Bsrc[3] + 2 * Dm, V_tT, 1024, 8,  1280, 1024, 1);

    proj_gemm_h<<<dim3(8, 32, 12), dim3(256), 0, stream>>>(pa);
  } else {
    ProjArgs pa;
    auto set = [&](int i, const float* X, const float* W, const float* Bv,
                   unsigned short* dst, int M, int lxsh, int Ld, int soff, int mode) {
      pa.d[i] = ProjDesc{X, W, Bv, dst, M, lxsh, Ld, soff, mode};
    };
    set(0,  vid, Wsrc[0],          Bsrc[0],          Qa_v, 4096, 10, 1024, 0,    0);
    set(1,  vid, Wsrc[0] + DD,     Bsrc[0] + Dm,     K_v,  4096, 10, 1280, 0,    0);
    set(2,  vid, Wsrc[0] + 2 * DD, Bsrc[0] + 2 * Dm, V_vT, 4096, 10, 1280, 0,    1);
    set(3,  vid, Wsrc[1],          Bsrc[1],          Qb_v, 4096, 10, 1024, 0,    0);
    set(4,  txt, Wsrc[1] + DD,     Bsrc[1] + Dm,     K_v,  1024, 8,  1280, 1024, 0);
    set(5,  txt, Wsrc[1] + 2 * DD, Bsrc[1] + 2 * Dm, V_vT, 1024, 8,  1280, 1024, 1);
    set(6,  txt, Wsrc[2],          Bsrc[2],          Qa_t, 1024, 8,  256,  0,    0);
    set(7,  vid, Wsrc[2] + DD,     Bsrc[2] + Dm,     K_t,  4096, 10, 1280, 0,    0);
    set(8,  vid, Wsrc[2] + 2 * DD, Bsrc[2] + 2 * Dm, V_tT, 4096, 10, 1280, 0,    1);
    set(9,  txt, Wsrc[3],          Bsrc[3],          Qb_t, 1024, 8,  256,  0,    0);
    set(10, txt, Wsrc[3] + DD,     Bsrc[3] + Dm,     K_t,  1024, 8,  1280, 1024, 0);
    set(11, txt, Wsrc[3] + 2 * DD, Bsrc[3] + 2 * Dm, V_tT, 1024, 8,  1280, 1024, 1);

    proj_gemm_f32<<<dim3(8, 32, 12), dim3(256), 0, stream>>>(pa);
  }

  // kbias AFTER proj (reuses the then-dead Xv_h region)
  make_kbias<<<dim3(5, 4), dim3(256), 0, stream>>>(vmask, tmask, kbias);

  float* out_v = (float*)d_out;
  float* out_t = out_v + 4 * 1024 * 1024;
  attn_flash3<<<dim3(80, 64), dim3(256), 0, stream>>>(
      Qa_v, Qb_v, K_v, V_vT, Qa_t, Qb_t, K_t, V_tT,
      vmask, tmask, kbias, out_v, out_t);
}